// Round 9
// baseline (58.964 us; speedup 1.0000x reference)
//
#include <hip/hip_runtime.h>

// MEASUREMENT ROUND: R7 fused kernel with phase B repeated 8x (asm-laundered,
// no CSE) so the kernel exceeds the harness fills' ~40 us and surfaces in the
// top-5 rocprof rows with its own counters. Output unchanged (min of 8
// identical passes). rocprof_dur = A + 8B; bench - rocprof = launch overhead.
//
// out[b,o] = min_i max(x[b,i], w[i,o])  — exact hard min via bucket-sorted
// early-exit scan (absmax 0.0 in R4-R8).

#define B_DIM 512
#define I_DIM 512
#define O_DIM 1024
#define NBUCK 256
#define REPS 8

#define RL(v_, l_) ((unsigned)__builtin_amdgcn_readlane((int)(v_), (l_)))
#define RFL(v_) ((unsigned)__builtin_amdgcn_readfirstlane((int)(v_)))

__global__ __launch_bounds__(1024, 8) void SmoothSTEMinMax_fused(
    const float* __restrict__ x,     // [B, I]
    const float* __restrict__ w,     // [I, O]
    float* __restrict__ out) {       // [B, O]
  __shared__ unsigned int hist[NBUCK];
  __shared__ unsigned int wssum[4];
  __shared__ unsigned int sdat[2 * I_DIM];   // [2e]=byteoff(i*4096), [2e+1]=valbits

  const int t = threadIdx.x;
  const int b = blockIdx.x;
  const int lane = t & 63;

  // ---- Phase A: counting sort by value bucket (threads 0..511 active) ----
  float xval = 0.0f;
  int bb = 0;
  if (t < I_DIM) {
    xval = x[b * I_DIM + t];
    bb = (int)(xval * 256.0f);
    bb = bb > 255 ? 255 : (bb < 0 ? 0 : bb);
  }
  if (t < NBUCK) hist[t] = 0;
  __syncthreads();
  if (t < I_DIM) atomicAdd(&hist[bb], 1u);
  __syncthreads();

  unsigned v = 0, cnt = 0;
  if (t < NBUCK) {
    cnt = hist[t];
    v = cnt;
#pragma unroll
    for (int d = 1; d < 64; d <<= 1) {
      const unsigned n = __shfl_up(v, d, 64);
      if (lane >= d) v += n;
    }
    if (lane == 63) wssum[t >> 6] = v;
  }
  __syncthreads();
  if (t < NBUCK) {
    unsigned add = 0;
#pragma unroll
    for (int ww = 0; ww < 4; ++ww)
      if (ww < (t >> 6)) add += wssum[ww];
    hist[t] = v + add - cnt;   // bucket cursor
  }
  __syncthreads();
  if (t < I_DIM) {
    const unsigned pos = atomicAdd(&hist[bb], 1u);
    sdat[2 * pos] = (unsigned)t * (unsigned)(O_DIM * 4);  // byte offset of w row
    sdat[2 * pos + 1] = __float_as_uint(xval);
  }
  __syncthreads();

  // ---- Phase B, repeated REPS times with laundered inputs ----
  const char* wb = reinterpret_cast<const char*>(w);
  const uint4 q0 = *reinterpret_cast<const uint4*>(&sdat[4 * lane]);

  float Afin = 3.402823466e+38f;

  for (int rep = 0; rep < REPS; ++rep) {
    // launder q and the o-offset so repeats cannot be CSE'd/DCE'd
    uint4 q = q0;
    unsigned o4 = (unsigned)t * 4u;
    asm volatile("" : "+v"(q.x), "+v"(q.y), "+v"(q.z), "+v"(q.w), "+v"(o4));

    float A = 3.402823466e+38f;

    // straight-line first 64 entries: zero checks, full global-load ILP
#pragma unroll
    for (int c = 0; c < 8; ++c) {
      float wv[8], xv[8];
#pragma unroll
      for (int e = 0; e < 8; ++e) {
        const int g = c * 8 + e;
        const unsigned off = RL((g & 1) ? q.z : q.x, g >> 1);
        const unsigned xb  = RL((g & 1) ? q.w : q.y, g >> 1);
        xv[e] = __uint_as_float(xb);
        wv[e] = *reinterpret_cast<const float*>(wb + (off + o4));
      }
#pragma unroll
      for (int e = 0; e < 8; ++e) A = fminf(A, fmaxf(xv[e], wv[e]));
    }

    int k = 64;
    // register-resident adaptive tail: entries 64..127, exit check per 8
#pragma unroll
    for (int c = 8; c < 16; ++c) {
      const float nx = __uint_as_float(RL(q.y, 4 * c));
      const float th = (float)(int)(nx * 256.0f) * 0.00390625f;
      if (!__any(A > th)) break;
#pragma unroll
      for (int e = 0; e < 8; ++e) {
        const int g = c * 8 + e;
        const unsigned off = RL((g & 1) ? q.z : q.x, g >> 1);
        const unsigned xb  = RL((g & 1) ? q.w : q.y, g >> 1);
        const float wvv = *reinterpret_cast<const float*>(wb + (off + o4));
        A = fminf(A, fmaxf(__uint_as_float(xb), wvv));
      }
      k += 8;
    }

    // LDS fallback: entries 128..511 (correctness only)
    if (k >= 128) {
      while (k < I_DIM) {
        const float nx = __uint_as_float(RFL(sdat[2 * k + 1]));
        const float th = (float)(int)(nx * 256.0f) * 0.00390625f;
        if (!__any(A > th)) break;
#pragma unroll
        for (int u = 0; u < 8; ++u) {
          const unsigned off = RFL(sdat[2 * (k + u)]);
          const unsigned xb  = RFL(sdat[2 * (k + u) + 1]);
          const float wvv = *reinterpret_cast<const float*>(wb + (off + o4));
          A = fminf(A, fmaxf(__uint_as_float(xb), wvv));
        }
        k += 8;
      }
    }

    Afin = fminf(Afin, A);   // all repeats identical -> result unchanged
  }

  out[b * O_DIM + t] = Afin;
}

extern "C" void kernel_launch(void* const* d_in, const int* in_sizes, int n_in,
                              void* d_out, int out_size, void* d_ws, size_t ws_size,
                              hipStream_t stream) {
  const float* x = (const float*)d_in[0];   // [512, 512]
  const float* w = (const float*)d_in[1];   // [512, 1024]
  float* out = (float*)d_out;               // [512, 1024]

  SmoothSTEMinMax_fused<<<B_DIM, 1024, 0, stream>>>(x, w, out);
}

// Round 10
// 15.221 us; speedup vs baseline: 3.8737x; 3.8737x over previous
//
#include <hip/hip_runtime.h>

// out[b,o] = min_i max(x[b,i], w[i,o])  — exact hard min via bucket-sorted
// early-exit scan (absmax 0.0, R4-R9).
//
// R9 decomposition: launch ovh ~3.8us, sort A ~3.3us, scan B ~6.5us.
// R10: (1) 2 rows/block, grid 256 = 1 block/CU -> sort runs in ONE device
// round (A ~halves); (2) scan does 2 outputs/lane with dwordx2 w-loads
// (halves VMEM instrs + amortizes readlane/address over 2 outputs).
//
// Phase A: counting-sort both rows into 256 value buckets in LDS.
// Phase B: 16 waves; wave w: row (w>>3), o-slice (w&7)*128 + lane*2.
//   Entries 0..127 in 4 VGPRs/lane (one uint4), broadcast via compile-time
//   v_readlane; first 64 straight-line (full load ILP), per-8 checked tail
//   64..127 (exit bound = next entry's bucket lower bound — exact), LDS
//   fallback beyond (never taken in practice).

#define B_DIM 512
#define I_DIM 512
#define O_DIM 1024
#define NBUCK 256

#define RL(v_, l_) ((unsigned)__builtin_amdgcn_readlane((int)(v_), (l_)))
#define RFL(v_) ((unsigned)__builtin_amdgcn_readfirstlane((int)(v_)))

typedef float float2v __attribute__((ext_vector_type(2)));

__global__ __launch_bounds__(1024, 8) void SmoothSTEMinMax_fused(
    const float* __restrict__ x,     // [B, I]
    const float* __restrict__ w,     // [I, O]
    float* __restrict__ out) {       // [B, O]
  __shared__ unsigned int hist[2][NBUCK];
  __shared__ unsigned int wssum[2][4];
  __shared__ uint2 sdat[2][I_DIM];   // {w-row byte offset, x valbits}, bucket-ordered

  const int t = threadIdx.x;
  const int blk = blockIdx.x;        // rows 2*blk, 2*blk+1
  const int lane = t & 63;
  const int r = t >> 9;              // which row this thread stages (0/1)
  const int idx = t & 511;

  // ---- Phase A: counting sort, both rows concurrently ----
  const float xval = x[(2 * blk + r) * I_DIM + idx];   // 4KB contiguous block load
  int bb = (int)(xval * 256.0f);
  bb = bb > 255 ? 255 : (bb < 0 ? 0 : bb);
  if (t < 512) hist[t >> 8][t & 255] = 0;
  __syncthreads();
  atomicAdd(&hist[r][bb], 1u);
  __syncthreads();

  // exclusive prefix sum per row (threads 0..511; each wave owns 64
  // consecutive buckets of one row)
  unsigned v = 0, cnt = 0;
  if (t < 512) {
    cnt = hist[t >> 8][t & 255];
    v = cnt;
#pragma unroll
    for (int d = 1; d < 64; d <<= 1) {
      const unsigned n = __shfl_up(v, d, 64);
      if (lane >= d) v += n;
    }
    if (lane == 63) wssum[t >> 8][(t & 255) >> 6] = v;
  }
  __syncthreads();
  if (t < 512) {
    unsigned add = 0;
#pragma unroll
    for (int ww = 0; ww < 4; ++ww)
      if (ww < ((t & 255) >> 6)) add += wssum[t >> 8][ww];
    hist[t >> 8][t & 255] = v + add - cnt;   // bucket cursor
  }
  __syncthreads();
  {
    const unsigned pos = atomicAdd(&hist[r][bb], 1u);
    sdat[r][pos] = make_uint2((unsigned)idx * (unsigned)(O_DIM * 4),
                              __float_as_uint(xval));
  }
  __syncthreads();

  // ---- Phase B: register-broadcast scan, 2 outputs per lane ----
  const int wv_ = t >> 6;            // 0..15
  const int br = wv_ >> 3;           // row select
  const int sl = wv_ & 7;            // o-slice
  const int orow = 2 * blk + br;
  const char* wb = reinterpret_cast<const char*>(w);
  const unsigned o8 = (unsigned)(sl * 128 + lane * 2) * 4u;  // invariant voffset

  // entries 0..127: lane l holds entries 2l (q.x=off,q.y=val), 2l+1 (q.z,q.w)
  const uint4 q = *reinterpret_cast<const uint4*>(&sdat[br][2 * lane]);

  float A0 = 3.402823466e+38f, A1 = A0;

  // straight-line first 64 entries: zero checks, full global-load ILP
#pragma unroll
  for (int c = 0; c < 8; ++c) {
    float2v wv2[8];
    float xv[8];
#pragma unroll
    for (int e = 0; e < 8; ++e) {
      const int g = c * 8 + e;
      const unsigned off = RL((g & 1) ? q.z : q.x, g >> 1);  // SGPR
      const unsigned xb  = RL((g & 1) ? q.w : q.y, g >> 1);  // SGPR
      xv[e] = __uint_as_float(xb);
      wv2[e] = *reinterpret_cast<const float2v*>(wb + (off + o8));
    }
#pragma unroll
    for (int e = 0; e < 8; ++e) {
      A0 = fminf(A0, fmaxf(xv[e], wv2[e].x));
      A1 = fminf(A1, fmaxf(xv[e], wv2[e].y));
    }
  }

  int k = 64;
  // register-resident adaptive tail: entries 64..127, exit check per 8
#pragma unroll
  for (int c = 8; c < 16; ++c) {
    const float nx = __uint_as_float(RL(q.y, 4 * c));          // value of entry 8c
    const float th = (float)(int)(nx * 256.0f) * 0.00390625f;  // bucket lower bound
    if (!__any(A0 > th || A1 > th)) break;                     // exact early exit
#pragma unroll
    for (int e = 0; e < 8; ++e) {
      const int g = c * 8 + e;
      const unsigned off = RL((g & 1) ? q.z : q.x, g >> 1);
      const unsigned xb  = RL((g & 1) ? q.w : q.y, g >> 1);
      const float2v wvv = *reinterpret_cast<const float2v*>(wb + (off + o8));
      A0 = fminf(A0, fmaxf(__uint_as_float(xb), wvv.x));
      A1 = fminf(A1, fmaxf(__uint_as_float(xb), wvv.y));
    }
    k += 8;
  }

  // LDS fallback: entries 128..511 (probability ~0; correctness only)
  if (k >= 128) {
    while (k < I_DIM) {
      const float nx = __uint_as_float(RFL(sdat[br][k].y));
      const float th = (float)(int)(nx * 256.0f) * 0.00390625f;
      if (!__any(A0 > th || A1 > th)) break;
#pragma unroll
      for (int u = 0; u < 8; ++u) {
        const unsigned off = RFL(sdat[br][k + u].x);
        const unsigned xb  = RFL(sdat[br][k + u].y);
        const float2v wvv = *reinterpret_cast<const float2v*>(wb + (off + o8));
        A0 = fminf(A0, fmaxf(__uint_as_float(xb), wvv.x));
        A1 = fminf(A1, fmaxf(__uint_as_float(xb), wvv.y));
      }
      k += 8;
    }
  }

  float2v res;
  res.x = A0;
  res.y = A1;
  *reinterpret_cast<float2v*>(&out[orow * O_DIM + sl * 128 + lane * 2]) = res;
}

extern "C" void kernel_launch(void* const* d_in, const int* in_sizes, int n_in,
                              void* d_out, int out_size, void* d_ws, size_t ws_size,
                              hipStream_t stream) {
  const float* x = (const float*)d_in[0];   // [512, 512]
  const float* w = (const float*)d_in[1];   // [512, 1024]
  float* out = (float*)d_out;               // [512, 1024]

  SmoothSTEMinMax_fused<<<B_DIM / 2, 1024, 0, stream>>>(x, w, out);
}

// Round 11
// 13.908 us; speedup vs baseline: 4.2397x; 1.0945x over previous
//
#include <hip/hip_runtime.h>

// out[b,o] = min_i max(x[b,i], w[i,o])  — exact hard min via bucket-sorted
// early-exit scan (absmax 0.0 since R4).
//
// R11: attack phase-A serialization (R9/R7 algebra: A ~7us, B ~6.5us).
//  - 64 value bins: prefix scan = ONE single-wave shfl scan (no cross-wave
//    combine). Exit bound floor(x*64)/64 still exact (lower-bounds unseen).
//  - 256-thread blocks (4 waves), grid (512 rows x 4 o-chunks) = 2048 blocks
//    = 8 blocks/CU = 32 waves/CU: A duplicated 4x per row, but each A is
//    4-wave-cheap and hides under other blocks' scan phase via TLP.
//  - Phase B identical to R7 (best measured): 1 output/lane, entries 0..127
//    in one uint4/lane, compile-time v_readlane broadcast, 64 straight-line,
//    per-8 checked tail, ~never-taken LDS fallback.

#define B_DIM 512
#define I_DIM 512
#define O_DIM 1024
#define NBUCK 64

#define RL(v_, l_) ((unsigned)__builtin_amdgcn_readlane((int)(v_), (l_)))
#define RFL(v_) ((unsigned)__builtin_amdgcn_readfirstlane((int)(v_)))

__global__ __launch_bounds__(256, 8) void SmoothSTEMinMax_fused(
    const float* __restrict__ x,     // [B, I]
    const float* __restrict__ w,     // [I, O]
    float* __restrict__ out) {       // [B, O]
  __shared__ unsigned int hist[NBUCK];
  __shared__ uint2 sdat[I_DIM];      // {w-row byte offset, x valbits}, bucket-ordered

  const int t = threadIdx.x;
  const int b = blockIdx.x;          // row
  const int lane = t & 63;

  // ---- Phase A: 64-bin counting sort (4 barriers, 1-wave prefix) ----
  const float xv0 = x[b * I_DIM + t];
  const float xv1 = x[b * I_DIM + 256 + t];
  int b0 = (int)(xv0 * 64.0f); b0 = b0 > 63 ? 63 : (b0 < 0 ? 0 : b0);
  int b1 = (int)(xv1 * 64.0f); b1 = b1 > 63 ? 63 : (b1 < 0 ? 0 : b1);

  if (t < NBUCK) hist[t] = 0;
  __syncthreads();
  atomicAdd(&hist[b0], 1u);
  atomicAdd(&hist[b1], 1u);
  __syncthreads();
  if (t < NBUCK) {                   // wave 0 only: shfl inclusive scan
    const unsigned cnt = hist[t];
    unsigned v = cnt;
#pragma unroll
    for (int d = 1; d < 64; d <<= 1) {
      const unsigned n = __shfl_up(v, d, 64);
      if (lane >= d) v += n;
    }
    hist[t] = v - cnt;               // exclusive base -> bucket cursor
  }
  __syncthreads();
  {
    const unsigned p0 = atomicAdd(&hist[b0], 1u);
    sdat[p0] = make_uint2((unsigned)t * (unsigned)(O_DIM * 4), __float_as_uint(xv0));
    const unsigned p1 = atomicAdd(&hist[b1], 1u);
    sdat[p1] = make_uint2((unsigned)(t + 256) * (unsigned)(O_DIM * 4),
                          __float_as_uint(xv1));
  }
  __syncthreads();

  // ---- Phase B: register-broadcast early-exit scan (R7 structure) ----
  const unsigned o4 = (unsigned)(blockIdx.y * 256 + t) * 4u;  // output byte offset
  const char* wb = reinterpret_cast<const char*>(w);
  float A = 3.402823466e+38f;

  // entries 0..127: lane l holds entries 2l (q.x=off,q.y=val), 2l+1 (q.z,q.w)
  const uint4 q = *reinterpret_cast<const uint4*>(&sdat[2 * lane]);

  // straight-line first 64 entries: zero checks, full global-load ILP
#pragma unroll
  for (int c = 0; c < 8; ++c) {
    float wv[8], xv[8];
#pragma unroll
    for (int e = 0; e < 8; ++e) {
      const int g = c * 8 + e;
      const unsigned off = RL((g & 1) ? q.z : q.x, g >> 1);
      const unsigned xb  = RL((g & 1) ? q.w : q.y, g >> 1);
      xv[e] = __uint_as_float(xb);
      wv[e] = *reinterpret_cast<const float*>(wb + (off + o4));
    }
#pragma unroll
    for (int e = 0; e < 8; ++e) A = fminf(A, fmaxf(xv[e], wv[e]));
  }

  int k = 64;
  // register-resident adaptive tail: entries 64..127, exit check per 8
#pragma unroll
  for (int c = 8; c < 16; ++c) {
    const float nx = __uint_as_float(RL(q.y, 4 * c));        // value of entry 8c
    const float th = (float)(int)(nx * 64.0f) * 0.015625f;   // bucket lower bound
    if (!__any(A > th)) break;                               // exact early exit
#pragma unroll
    for (int e = 0; e < 8; ++e) {
      const int g = c * 8 + e;
      const unsigned off = RL((g & 1) ? q.z : q.x, g >> 1);
      const unsigned xb  = RL((g & 1) ? q.w : q.y, g >> 1);
      const float wvv = *reinterpret_cast<const float*>(wb + (off + o4));
      A = fminf(A, fmaxf(__uint_as_float(xb), wvv));
    }
    k += 8;
  }

  // LDS fallback: entries 128..511 (probability ~0; correctness only)
  if (k >= 128) {
    while (k < I_DIM) {
      const float nx = __uint_as_float(RFL(sdat[k].y));
      const float th = (float)(int)(nx * 64.0f) * 0.015625f;
      if (!__any(A > th)) break;
#pragma unroll
      for (int u = 0; u < 8; ++u) {
        const unsigned off = RFL(sdat[k + u].x);
        const unsigned xb  = RFL(sdat[k + u].y);
        const float wvv = *reinterpret_cast<const float*>(wb + (off + o4));
        A = fminf(A, fmaxf(__uint_as_float(xb), wvv));
      }
      k += 8;
    }
  }

  out[b * O_DIM + blockIdx.y * 256 + t] = A;
}

extern "C" void kernel_launch(void* const* d_in, const int* in_sizes, int n_in,
                              void* d_out, int out_size, void* d_ws, size_t ws_size,
                              hipStream_t stream) {
  const float* x = (const float*)d_in[0];   // [512, 512]
  const float* w = (const float*)d_in[1];   // [512, 1024]
  float* out = (float*)d_out;               // [512, 1024]

  dim3 grid(B_DIM, O_DIM / 256);            // 512 x 4 = 2048 blocks, 4 waves each
  SmoothSTEMinMax_fused<<<grid, 256, 0, stream>>>(x, w, out);
}